// Round 3
// baseline (501.042 us; speedup 1.0000x reference)
//
#include <hip/hip_runtime.h>
#include <hip/hip_bf16.h>

#define N_NODES 50000
#define N_EDGES 1600000
#define HEADS 4
#define NEG_SLOPE 0.2f
#define CAP 16384          // max |A1| (actual ~2100)
#define CAPDEG 512         // max staged in-degree in agg
#define MCSR_CAP (1 << 20) // mini edge-list capacity (actual ~69K)
#define NCOL 144           // 128 output cols + 16 alpha cols (8 used)
#define WT_L (NCOL * 128)  // per-layer wt elements

typedef short short8 __attribute__((ext_vector_type(8)));
typedef float f32x4 __attribute__((ext_vector_type(4)));

__device__ __forceinline__ float leaky(float x) { return fmaxf(x, NEG_SLOPE * x); }

__device__ __forceinline__ unsigned short f2bf(float f) {
    unsigned int u = __builtin_bit_cast(unsigned int, f);
    u += 0x7fffu + ((u >> 16) & 1u);           // RNE to bf16
    return (unsigned short)(u >> 16);
}
__device__ __forceinline__ float bf2f(unsigned short s) {
    unsigned int u = ((unsigned int)s) << 16;
    return __builtin_bit_cast(float, u);
}

// ---------------- prep: W -> transposed bf16 hi/lo [layer][col][k], alpha cols fused;
// also marks roots ----------------

__global__ void prep_kernel(const float* __restrict__ W1, const float* __restrict__ a1s,
                            const float* __restrict__ a1d,
                            const float* __restrict__ W2, const float* __restrict__ a2s,
                            const float* __restrict__ a2d,
                            unsigned short* __restrict__ wt_hi, unsigned short* __restrict__ wt_lo,
                            const int* __restrict__ roots,
                            int* __restrict__ flagR, int* __restrict__ flag1) {
    int idx = blockIdx.x * 256 + threadIdx.x;       // 2*144*128 = 36864 total
    int layer = idx / WT_L;
    int rem = idx - layer * WT_L;
    int col = rem >> 7;
    int k = rem & 127;
    const float* W = layer ? W2 : W1;
    const float* as = layer ? a2s : a1s;
    const float* ad = layer ? a2d : a1d;
    float w = 0.f;
    if (col < 128) {
        w = W[k * 128 + col];
    } else if (col < 136) {
        int j = col - 128;
        int h = j & 3;
        const float* av = (j < 4) ? as : ad;
        float s = 0.f;
        for (int d = 0; d < 32; ++d) s += W[k * 128 + h * 32 + d] * av[h * 32 + d];
        w = s;
    }
    unsigned short hb = f2bf(w);
    wt_hi[idx] = hb;
    wt_lo[idx] = f2bf(w - bf2f(hb));
    if (blockIdx.x == 0 && threadIdx.x < 64) {
        int n = roots[threadIdx.x];
        flagR[n] = 1;
        flag1[n] = 1;
    }
}

// ---------------- active-set construction ----------------

__global__ void passA_kernel(const int* __restrict__ ei, const int* __restrict__ flagR,
                             int* __restrict__ flag1) {
    int i = blockIdx.x * blockDim.x + threadIdx.x;
    if (i * 4 >= N_EDGES) return;
    int4 d4 = ((const int4*)(ei + N_EDGES))[i];
    if (flagR[d4.x]) flag1[ei[4 * i + 0]] = 1;
    if (flagR[d4.y]) flag1[ei[4 * i + 1]] = 1;
    if (flagR[d4.z]) flag1[ei[4 * i + 2]] = 1;
    if (flagR[d4.w]) flag1[ei[4 * i + 3]] = 1;
}

__global__ void compact_kernel(const int* __restrict__ flag1, int* __restrict__ cnt,
                               int* __restrict__ list, int* __restrict__ inv) {
    int i = blockIdx.x * blockDim.x + threadIdx.x;
    if (i < N_NODES && flag1[i]) {
        int p = atomicAdd(cnt, 1);
        if (p < CAP) { list[p] = i; inv[i] = p; }
    }
}

// append (src,row) pairs for edges into A1 + count degrees (single 1.6M pass)
__global__ void passB_kernel(const int* __restrict__ ei, const int* __restrict__ flag1,
                             const int* __restrict__ inv, int* __restrict__ ecnt,
                             int* __restrict__ esrc, int* __restrict__ erow,
                             int* __restrict__ mdeg) {
    int i = blockIdx.x * blockDim.x + threadIdx.x;
    if (i * 4 >= N_EDGES) return;
    int4 d4 = ((const int4*)(ei + N_EDGES))[i];
    int dd[4] = {d4.x, d4.y, d4.z, d4.w};
#pragma unroll
    for (int j = 0; j < 4; ++j) {
        if (flag1[dd[j]]) {
            int row = inv[dd[j]];
            int p = atomicAdd(ecnt, 1);
            if (p < MCSR_CAP) {
                esrc[p] = ei[4 * i + j];
                erow[p] = row;
                atomicAdd(&mdeg[row], 1);
            }
        }
    }
}

__global__ __launch_bounds__(1024) void mini_scan_kernel(const int* __restrict__ mdeg,
                                                         const int* __restrict__ cntp,
                                                         int* __restrict__ moff,
                                                         int* __restrict__ mcur) {
    __shared__ int sums[1024];
    int cnt = *cntp;
    int chunk = (cnt + 1023) >> 10;
    int t = threadIdx.x;
    int begin = t * chunk;
    int endi = begin + chunk; if (endi > cnt) endi = cnt;
    int s = 0;
    for (int i = begin; i < endi; ++i) s += mdeg[i];
    sums[t] = s;
    __syncthreads();
    for (int o = 1; o < 1024; o <<= 1) {
        int x = (t >= o) ? sums[t - o] : 0;
        __syncthreads();
        sums[t] += x;
        __syncthreads();
    }
    int excl = sums[t] - s;
    for (int i = begin; i < endi; ++i) {
        int d = mdeg[i];
        moff[i] = excl; mcur[i] = excl;
        excl += d;
    }
    if (t == 1023) moff[cnt] = sums[1023];
}

__global__ void scatter_mini_kernel(const int* __restrict__ ecnt,
                                    const int* __restrict__ esrc, const int* __restrict__ erow,
                                    int* __restrict__ mcur, int* __restrict__ mcsr) {
    int total = *ecnt; if (total > MCSR_CAP) total = MCSR_CAP;
    int stride = gridDim.x * blockDim.x;
    for (int i = blockIdx.x * blockDim.x + threadIdx.x; i < total; i += stride) {
        int row = erow[i];
        int p = atomicAdd(&mcur[row], 1);
        mcsr[p] = esrc[i];
    }
}

// ---------------- MFMA GEMM (bf16x3 split) + fused alpha columns ----------------
// Tile: 128 rows x 144 cols per block (cols 128-135 are alpha_s/alpha_d).
// 4 waves; wave w: rows w*32..w*32+31 (2 row-tiles of 16), all 9 col-tiles of 16.
// W (bf16 hi/lo, transposed [col][k]) fully LDS-resident, XOR-swizzled.

template <int RELU, int DYN>
__global__ __launch_bounds__(256, 2) void gemm_kernel(const float* __restrict__ A,
                                                      const unsigned short* __restrict__ wt_hi,
                                                      const unsigned short* __restrict__ wt_lo,
                                                      float* __restrict__ H,
                                                      float* __restrict__ aS,
                                                      float* __restrict__ aD,
                                                      int n_static, const int* __restrict__ cntp) {
    __shared__ short lds[2 * WT_L];   // hi | lo, 72 KB
    int n = DYN ? *cntp : n_static;
    int ntiles = (n + 127) >> 7;
    int t = threadIdx.x;
    // stage W hi/lo (16B granules, swizzled)
    for (int s = t; s < 2 * NCOL * 16; s += 256) {
        int half = s >= NCOL * 16;
        int rem = half ? s - NCOL * 16 : s;
        int col = rem >> 4;
        int kblk = rem & 15;
        const unsigned short* src = half ? wt_lo : wt_hi;
        short8 v = *(const short8*)(src + col * 128 + kblk * 8);
        int idx = ((col * 128 + kblk * 8) ^ ((col & 7) << 3)) + half * WT_L;
        *(short8*)(lds + idx) = v;
    }
    __syncthreads();
    int w = t >> 6;
    int l = t & 63;
    int lr = l & 15;
    int lq = l >> 4;
    for (int tile = blockIdx.x; tile < ntiles; tile += gridDim.x) {
        int row0 = tile * 128 + w * 32;
        f32x4 acc[2][9];
#pragma unroll
        for (int rt = 0; rt < 2; ++rt)
#pragma unroll
            for (int ct = 0; ct < 9; ++ct)
                acc[rt][ct] = (f32x4){0.f, 0.f, 0.f, 0.f};
#pragma unroll
        for (int kk = 0; kk < 4; ++kk) {
            short8 ah[2], al[2];
#pragma unroll
            for (int rt = 0; rt < 2; ++rt) {
                int gr = row0 + rt * 16 + lr;
                float4 p0 = make_float4(0.f, 0.f, 0.f, 0.f);
                float4 p1 = make_float4(0.f, 0.f, 0.f, 0.f);
                if (gr < n) {
                    const float* p = A + (size_t)gr * 128 + kk * 32 + lq * 8;
                    p0 = *(const float4*)p;
                    p1 = *(const float4*)(p + 4);
                }
                float xv[8] = {p0.x, p0.y, p0.z, p0.w, p1.x, p1.y, p1.z, p1.w};
#pragma unroll
                for (int j = 0; j < 8; ++j) {
                    float f = RELU ? fmaxf(xv[j], 0.f) : xv[j];
                    unsigned short hb = f2bf(f);
                    ah[rt][j] = (short)hb;
                    al[rt][j] = (short)f2bf(f - bf2f(hb));
                }
            }
#pragma unroll
            for (int ct = 0; ct < 9; ++ct) {
                int col = ct * 16 + lr;
                int base = (col * 128 + kk * 32 + lq * 8) ^ ((col & 7) << 3);
                short8 bh = *(const short8*)(lds + base);
                short8 bl = *(const short8*)(lds + base + WT_L);
#pragma unroll
                for (int rt = 0; rt < 2; ++rt) {
                    acc[rt][ct] = __builtin_amdgcn_mfma_f32_16x16x32_bf16(ah[rt], bh, acc[rt][ct], 0, 0, 0);
                    acc[rt][ct] = __builtin_amdgcn_mfma_f32_16x16x32_bf16(ah[rt], bl, acc[rt][ct], 0, 0, 0);
                    acc[rt][ct] = __builtin_amdgcn_mfma_f32_16x16x32_bf16(al[rt], bh, acc[rt][ct], 0, 0, 0);
                }
            }
        }
        // epilogue: C layout col = lane&15, row = (lane>>4)*4 + reg  [m89-verified]
#pragma unroll
        for (int rt = 0; rt < 2; ++rt) {
            int rbase = row0 + rt * 16 + lq * 4;
#pragma unroll
            for (int ct = 0; ct < 8; ++ct) {
                int col = ct * 16 + lr;
#pragma unroll
                for (int r = 0; r < 4; ++r) {
                    int gr = rbase + r;
                    if (gr < n) H[(size_t)gr * 128 + col] = acc[rt][ct][r];
                }
            }
#pragma unroll
            for (int r = 0; r < 4; ++r) {
                int gr = rbase + r;
                if (gr < n && lr < 8) {
                    float v = acc[rt][8][r];
                    if (lr < 4) aS[gr * 4 + lr] = v;
                    else        aD[gr * 4 + (lr - 4)] = v;
                }
            }
        }
    }
}

// ---------------- pull aggregation (unchanged from R1 — verified) ----------------

template <int MODE>
__global__ __launch_bounds__(128) void agg_kernel(const float* __restrict__ H,
                                                  const float* __restrict__ aS,
                                                  const float* __restrict__ aD,
                                                  const int* __restrict__ moff,
                                                  const int* __restrict__ mcsr,
                                                  const float* __restrict__ bias,
                                                  const int* __restrict__ list,
                                                  const int* __restrict__ inv,
                                                  const int* __restrict__ cntp,
                                                  float* __restrict__ out) {
    __shared__ int s_src[CAPDEG];
    __shared__ float s_as[CAPDEG * 4];
    __shared__ float s_w[4][CAPDEG];
    int t = threadIdx.x;
    int head = t >> 5;
    int jl = t & 31;
    int cnt = MODE ? 64 : *cntp;
    float bval = bias[t];
    for (int j = blockIdx.x; j < cnt; j += gridDim.x) {
        int n = list[j];
        int row = MODE ? inv[n] : j;
        int own = MODE ? row : n;
        int start = moff[row];
        int deg = moff[row + 1] - start;
        float ad_n = aD[own * HEADS + head];
        float as_self = aS[own * HEADS + head];
        float e_self = leaky(as_self + ad_n);
        float denom, acc;

        if (deg <= CAPDEG) {
            for (int i = t; i < deg; i += 128) {
                int s = mcsr[start + i];
                int si = MODE ? inv[s] : s;
                s_src[i] = si;
                ((float4*)s_as)[i] = ((const float4*)aS)[si];
            }
            __syncthreads();
            float lm = e_self;
            for (int i = jl; i < deg; i += 32)
                lm = fmaxf(lm, leaky(s_as[i * 4 + head] + ad_n));
#pragma unroll
            for (int msk = 16; msk > 0; msk >>= 1)
                lm = fmaxf(lm, __shfl_xor(lm, msk, 32));
            float lsum = 0.f;
            for (int i = jl; i < deg; i += 32) {
                float ww = __expf(leaky(s_as[i * 4 + head] + ad_n) - lm);
                s_w[head][i] = ww;
                lsum += ww;
            }
#pragma unroll
            for (int msk = 16; msk > 0; msk >>= 1)
                lsum += __shfl_xor(lsum, msk, 32);
            float w_self = __expf(e_self - lm);
            denom = lsum + w_self;
            __syncthreads();
            acc = w_self * H[(size_t)own * 128 + t];
            for (int i = 0; i < deg; ++i)
                acc += s_w[head][i] * H[(size_t)s_src[i] * 128 + t];
        } else {
            float m = e_self;
            for (int e = start; e < start + deg; ++e) {
                int s = mcsr[e];
                int si = MODE ? inv[s] : s;
                m = fmaxf(m, leaky(aS[si * HEADS + head] + ad_n));
            }
            float w_self = __expf(e_self - m);
            denom = w_self;
            acc = w_self * H[(size_t)own * 128 + t];
            for (int e = start; e < start + deg; ++e) {
                int s = mcsr[e];
                int si = MODE ? inv[s] : s;
                float ww = __expf(leaky(aS[si * HEADS + head] + ad_n) - m);
                denom += ww;
                acc += ww * H[(size_t)si * 128 + t];
            }
        }
        out[(size_t)j * 128 + t] = acc / denom + bval;
        __syncthreads();
    }
}

// ---------------- launch ----------------

extern "C" void kernel_launch(void* const* d_in, const int* in_sizes, int n_in,
                              void* d_out, int out_size, void* d_ws, size_t ws_size,
                              hipStream_t stream) {
    const float* x   = (const float*)d_in[0];
    const int*   ei  = (const int*)d_in[1];
    const int*   rts = (const int*)d_in[2];
    const float* W1  = (const float*)d_in[3];
    const float* a1s = (const float*)d_in[4];
    const float* a1d = (const float*)d_in[5];
    const float* b1  = (const float*)d_in[6];
    const float* W2  = (const float*)d_in[7];
    const float* a2s = (const float*)d_in[8];
    const float* a2d = (const float*)d_in[9];
    const float* b2  = (const float*)d_in[10];
    float* out = (float*)d_out;

    char* ws = (char*)d_ws;
    size_t o = 0;
    auto alloc = [&](size_t bytes) -> void* {
        void* p = ws + o;
        o += (bytes + 255) & ~(size_t)255;
        return p;
    };
    // zero region: flagR | flag1 | cnt | ecnt | mdeg
    int* flagR = (int*)alloc((size_t)N_NODES * 4);
    int* flag1 = (int*)alloc((size_t)N_NODES * 4);
    int* cnt   = (int*)alloc(4);
    int* ecnt  = (int*)alloc(4);
    int* mdeg  = (int*)alloc((size_t)CAP * 4);
    size_t zlen = o;
    int* list  = (int*)alloc((size_t)CAP * 4);
    int* inv   = (int*)alloc((size_t)N_NODES * 4);
    int* moff  = (int*)alloc((size_t)(CAP + 1) * 4);
    int* mcur  = (int*)alloc((size_t)CAP * 4);
    int* mcsr  = (int*)alloc((size_t)MCSR_CAP * 4);
    int* esrc  = (int*)alloc((size_t)MCSR_CAP * 4);
    int* erow  = (int*)alloc((size_t)MCSR_CAP * 4);
    unsigned short* wt_hi = (unsigned short*)alloc((size_t)2 * WT_L * 2);
    unsigned short* wt_lo = (unsigned short*)alloc((size_t)2 * WT_L * 2);
    float* h1  = (float*)alloc((size_t)N_NODES * 128 * 4);
    float* aS1 = (float*)alloc((size_t)N_NODES * HEADS * 4);
    float* aD1 = (float*)alloc((size_t)N_NODES * HEADS * 4);
    float* o1c = (float*)alloc((size_t)CAP * 128 * 4);
    float* h2c = (float*)alloc((size_t)CAP * 128 * 4);
    float* aS2 = (float*)alloc((size_t)CAP * HEADS * 4);
    float* aD2 = (float*)alloc((size_t)CAP * HEADS * 4);

    hipMemsetAsync(ws, 0, zlen, stream);

    const int EB = (N_EDGES / 4 + 255) / 256;

    prep_kernel<<<144, 256, 0, stream>>>(W1, a1s, a1d, W2, a2s, a2d,
                                         wt_hi, wt_lo, rts, flagR, flag1);
    passA_kernel<<<EB, 256, 0, stream>>>(ei, flagR, flag1);
    compact_kernel<<<(N_NODES + 255) / 256, 256, 0, stream>>>(flag1, cnt, list, inv);
    passB_kernel<<<EB, 256, 0, stream>>>(ei, flag1, inv, ecnt, esrc, erow, mdeg);
    mini_scan_kernel<<<1, 1024, 0, stream>>>(mdeg, cnt, moff, mcur);
    scatter_mini_kernel<<<128, 256, 0, stream>>>(ecnt, esrc, erow, mcur, mcsr);

    // layer 1
    gemm_kernel<0, 0><<<(N_NODES + 127) / 128, 256, 0, stream>>>(
        x, wt_hi, wt_lo, h1, aS1, aD1, N_NODES, nullptr);
    agg_kernel<0><<<2048, 128, 0, stream>>>(h1, aS1, aD1, moff, mcsr, b1, list, inv, cnt, o1c);

    // layer 2
    gemm_kernel<1, 1><<<32, 256, 0, stream>>>(
        o1c, wt_hi + WT_L, wt_lo + WT_L, h2c, aS2, aD2, 0, cnt);
    agg_kernel<1><<<64, 128, 0, stream>>>(h2c, aS2, aD2, moff, mcsr, b2, rts, inv, cnt, out);
}

// Round 4
// 244.945 us; speedup vs baseline: 2.0455x; 2.0455x over previous
//
#include <hip/hip_runtime.h>
#include <hip/hip_bf16.h>

#define N_NODES 50000
#define N_EDGES 1600000
#define HEADS 4
#define NEG_SLOPE 0.2f
#define CAP 16384          // max |A1| (actual ~2100)
#define CAPDEG 512         // max staged in-degree in agg
#define MCSR_CAP (1 << 20) // mini edge-list capacity (actual ~69K)
#define NCOL 144           // 128 output cols + 16 alpha cols (8 used)
#define WT_L (NCOL * 128)  // per-layer wt elements
#define NBW 784            // u64 words for 50176-bit node mask

typedef short short8 __attribute__((ext_vector_type(8)));
typedef float f32x4 __attribute__((ext_vector_type(4)));

__device__ __forceinline__ float leaky(float x) { return fmaxf(x, NEG_SLOPE * x); }

__device__ __forceinline__ unsigned short f2bf(float f) {
    unsigned int u = __builtin_bit_cast(unsigned int, f);
    u += 0x7fffu + ((u >> 16) & 1u);           // RNE to bf16
    return (unsigned short)(u >> 16);
}
__device__ __forceinline__ float bf2f(unsigned short s) {
    unsigned int u = ((unsigned int)s) << 16;
    return __builtin_bit_cast(float, u);
}

// ---------------- prep: W -> transposed bf16 hi/lo [layer][col][k], alpha cols fused;
// also marks roots (bitmask + int flags) ----------------

__global__ void prep_kernel(const float* __restrict__ W1, const float* __restrict__ a1s,
                            const float* __restrict__ a1d,
                            const float* __restrict__ W2, const float* __restrict__ a2s,
                            const float* __restrict__ a2d,
                            unsigned short* __restrict__ wt_hi, unsigned short* __restrict__ wt_lo,
                            const int* __restrict__ roots,
                            unsigned long long* __restrict__ rbits,
                            int* __restrict__ flag1) {
    int idx = blockIdx.x * 256 + threadIdx.x;       // 2*144*128 = 36864 total
    int layer = idx / WT_L;
    int rem = idx - layer * WT_L;
    int col = rem >> 7;
    int k = rem & 127;
    const float* W = layer ? W2 : W1;
    const float* as = layer ? a2s : a1s;
    const float* ad = layer ? a2d : a1d;
    float w = 0.f;
    if (col < 128) {
        w = W[k * 128 + col];
    } else if (col < 136) {
        int j = col - 128;
        int h = j & 3;
        const float* av = (j < 4) ? as : ad;
        float s = 0.f;
        for (int d = 0; d < 32; ++d) s += W[k * 128 + h * 32 + d] * av[h * 32 + d];
        w = s;
    }
    unsigned short hb = f2bf(w);
    wt_hi[idx] = hb;
    wt_lo[idx] = f2bf(w - bf2f(hb));
    if (blockIdx.x == 0 && threadIdx.x < 64) {
        int n = roots[threadIdx.x];
        atomicOr(&rbits[n >> 6], 1ull << (n & 63));
        flag1[n] = 1;
    }
}

// ---------------- pass A: flag1[src]=1 for edges whose dst is a root ----------------
// root bitmask staged in LDS; edge stream fully coalesced.

__global__ __launch_bounds__(256) void passA_kernel(const int* __restrict__ ei,
                                                    const unsigned long long* __restrict__ rbits,
                                                    int* __restrict__ flag1) {
    __shared__ unsigned long long lmask[NBW];
    int t = threadIdx.x;
    for (int w = t; w < NBW; w += 256) lmask[w] = rbits[w];
    __syncthreads();
    int i = blockIdx.x * 256 + t;
    if (i * 4 >= N_EDGES) return;
    int4 s4 = ((const int4*)ei)[i];
    int4 d4 = ((const int4*)(ei + N_EDGES))[i];
    int ss[4] = {s4.x, s4.y, s4.z, s4.w};
    int dd[4] = {d4.x, d4.y, d4.z, d4.w};
#pragma unroll
    for (int j = 0; j < 4; ++j)
        if ((lmask[dd[j] >> 6] >> (dd[j] & 63)) & 1ull) flag1[ss[j]] = 1;
}

// ---------------- compact: wave-aggregated; also emits flag1 bitmask ----------------

__global__ __launch_bounds__(256) void compact_kernel(const int* __restrict__ flag1,
                                                      int* __restrict__ cnt,
                                                      int* __restrict__ list,
                                                      int* __restrict__ inv,
                                                      unsigned long long* __restrict__ f1bits) {
    int i = blockIdx.x * blockDim.x + threadIdx.x;
    int lane = threadIdx.x & 63;
    int f = (i < N_NODES) ? flag1[i] : 0;
    unsigned long long b = __ballot(f != 0);
    if (lane == 0) f1bits[i >> 6] = b;
    if (b) {
        int leader = (int)(__ffsll((long long)b) - 1);
        int base = 0;
        if (lane == leader) base = atomicAdd(cnt, __popcll(b));
        base = __shfl(base, leader, 64);
        if (f) {
            int p = base + __popcll(b & ((1ull << lane) - 1ull));
            if (p < CAP) { list[p] = i; inv[i] = p; }
        }
    }
}

// ---------------- pass E: append (src,row) for edges into A1; block-aggregated ----------------

__global__ __launch_bounds__(256) void passE_kernel(const int* __restrict__ ei,
                                                    const unsigned long long* __restrict__ f1bits,
                                                    const int* __restrict__ inv,
                                                    int* __restrict__ ecnt,
                                                    int* __restrict__ esrc, int* __restrict__ erow,
                                                    int* __restrict__ mdeg) {
    __shared__ unsigned long long lmask[NBW];
    __shared__ int bufS[1024], bufD[1024];
    __shared__ int lcnt, gbase;
    int t = threadIdx.x;
    for (int w = t; w < NBW; w += 256) lmask[w] = f1bits[w];
    if (t == 0) lcnt = 0;
    __syncthreads();
    int i = blockIdx.x * 256 + t;
    if (i * 4 < N_EDGES) {
        int4 s4 = ((const int4*)ei)[i];
        int4 d4 = ((const int4*)(ei + N_EDGES))[i];
        int ss[4] = {s4.x, s4.y, s4.z, s4.w};
        int dd[4] = {d4.x, d4.y, d4.z, d4.w};
#pragma unroll
        for (int j = 0; j < 4; ++j) {
            if ((lmask[dd[j] >> 6] >> (dd[j] & 63)) & 1ull) {
                int p = atomicAdd(&lcnt, 1);     // LDS atomic: cheap
                bufS[p] = ss[j]; bufD[p] = dd[j];
            }
        }
    }
    __syncthreads();
    if (t == 0) gbase = atomicAdd(ecnt, lcnt);   // ONE global atomic per block
    __syncthreads();
    int base = gbase, m = lcnt;
    for (int k = t; k < m; k += 256) {
        int p = base + k;
        if (p < MCSR_CAP) {
            int row = inv[bufD[k]];
            esrc[p] = bufS[k];
            erow[p] = row;
            atomicAdd(&mdeg[row], 1);            // distributed over ~2100 rows
        }
    }
}

__global__ __launch_bounds__(1024) void mini_scan_kernel(const int* __restrict__ mdeg,
                                                         const int* __restrict__ cntp,
                                                         int* __restrict__ moff,
                                                         int* __restrict__ mcur) {
    __shared__ int sums[1024];
    int cnt = *cntp;
    int chunk = (cnt + 1023) >> 10;
    int t = threadIdx.x;
    int begin = t * chunk;
    int endi = begin + chunk; if (endi > cnt) endi = cnt;
    int s = 0;
    for (int i = begin; i < endi; ++i) s += mdeg[i];
    sums[t] = s;
    __syncthreads();
    for (int o = 1; o < 1024; o <<= 1) {
        int x = (t >= o) ? sums[t - o] : 0;
        __syncthreads();
        sums[t] += x;
        __syncthreads();
    }
    int excl = sums[t] - s;
    for (int i = begin; i < endi; ++i) {
        int d = mdeg[i];
        moff[i] = excl; mcur[i] = excl;
        excl += d;
    }
    if (t == 1023) moff[cnt] = sums[1023];
}

__global__ void scatter_mini_kernel(const int* __restrict__ ecnt,
                                    const int* __restrict__ esrc, const int* __restrict__ erow,
                                    int* __restrict__ mcur, int* __restrict__ mcsr) {
    int total = *ecnt; if (total > MCSR_CAP) total = MCSR_CAP;
    int stride = gridDim.x * blockDim.x;
    for (int i = blockIdx.x * blockDim.x + threadIdx.x; i < total; i += stride) {
        int row = erow[i];
        int p = atomicAdd(&mcur[row], 1);
        mcsr[p] = esrc[i];
    }
}

// ---------------- MFMA GEMM (bf16x4 split) + fused alpha columns ----------------

template <int RELU, int DYN>
__global__ __launch_bounds__(256, 2) void gemm_kernel(const float* __restrict__ A,
                                                      const unsigned short* __restrict__ wt_hi,
                                                      const unsigned short* __restrict__ wt_lo,
                                                      float* __restrict__ H,
                                                      float* __restrict__ aS,
                                                      float* __restrict__ aD,
                                                      int n_static, const int* __restrict__ cntp) {
    __shared__ short lds[2 * WT_L];   // hi | lo, 72 KB
    int n = DYN ? *cntp : n_static;
    int ntiles = (n + 127) >> 7;
    int t = threadIdx.x;
    for (int s = t; s < 2 * NCOL * 16; s += 256) {
        int half = s >= NCOL * 16;
        int rem = half ? s - NCOL * 16 : s;
        int col = rem >> 4;
        int kblk = rem & 15;
        const unsigned short* src = half ? wt_lo : wt_hi;
        short8 v = *(const short8*)(src + col * 128 + kblk * 8);
        int idx = ((col * 128 + kblk * 8) ^ ((col & 7) << 3)) + half * WT_L;
        *(short8*)(lds + idx) = v;
    }
    __syncthreads();
    int w = t >> 6;
    int l = t & 63;
    int lr = l & 15;
    int lq = l >> 4;
    for (int tile = blockIdx.x; tile < ntiles; tile += gridDim.x) {
        int row0 = tile * 128 + w * 32;
        f32x4 acc[2][9];
#pragma unroll
        for (int rt = 0; rt < 2; ++rt)
#pragma unroll
            for (int ct = 0; ct < 9; ++ct)
                acc[rt][ct] = (f32x4){0.f, 0.f, 0.f, 0.f};
#pragma unroll
        for (int kk = 0; kk < 4; ++kk) {
            short8 ah[2], al[2];
#pragma unroll
            for (int rt = 0; rt < 2; ++rt) {
                int gr = row0 + rt * 16 + lr;
                float4 p0 = make_float4(0.f, 0.f, 0.f, 0.f);
                float4 p1 = make_float4(0.f, 0.f, 0.f, 0.f);
                if (gr < n) {
                    const float* p = A + (size_t)gr * 128 + kk * 32 + lq * 8;
                    p0 = *(const float4*)p;
                    p1 = *(const float4*)(p + 4);
                }
                float xv[8] = {p0.x, p0.y, p0.z, p0.w, p1.x, p1.y, p1.z, p1.w};
#pragma unroll
                for (int j = 0; j < 8; ++j) {
                    float f = RELU ? fmaxf(xv[j], 0.f) : xv[j];
                    unsigned short hb = f2bf(f);
                    ah[rt][j] = (short)hb;
                    al[rt][j] = (short)f2bf(f - bf2f(hb));
                }
            }
#pragma unroll
            for (int ct = 0; ct < 9; ++ct) {
                int col = ct * 16 + lr;
                int base = (col * 128 + kk * 32 + lq * 8) ^ ((col & 7) << 3);
                short8 bh = *(const short8*)(lds + base);
                short8 bl = *(const short8*)(lds + base + WT_L);
#pragma unroll
                for (int rt = 0; rt < 2; ++rt) {
                    acc[rt][ct] = __builtin_amdgcn_mfma_f32_16x16x32_bf16(ah[rt], bh, acc[rt][ct], 0, 0, 0);
                    acc[rt][ct] = __builtin_amdgcn_mfma_f32_16x16x32_bf16(ah[rt], bl, acc[rt][ct], 0, 0, 0);
                    acc[rt][ct] = __builtin_amdgcn_mfma_f32_16x16x32_bf16(al[rt], bh, acc[rt][ct], 0, 0, 0);
                    acc[rt][ct] = __builtin_amdgcn_mfma_f32_16x16x32_bf16(al[rt], bl, acc[rt][ct], 0, 0, 0);
                }
            }
        }
        // epilogue: C layout col = lane&15, row = (lane>>4)*4 + reg  [m89-verified]
#pragma unroll
        for (int rt = 0; rt < 2; ++rt) {
            int rbase = row0 + rt * 16 + lq * 4;
#pragma unroll
            for (int ct = 0; ct < 8; ++ct) {
                int col = ct * 16 + lr;
#pragma unroll
                for (int r = 0; r < 4; ++r) {
                    int gr = rbase + r;
                    if (gr < n) H[(size_t)gr * 128 + col] = acc[rt][ct][r];
                }
            }
#pragma unroll
            for (int r = 0; r < 4; ++r) {
                int gr = rbase + r;
                if (gr < n && lr < 8) {
                    float v = acc[rt][8][r];
                    if (lr < 4) aS[gr * 4 + lr] = v;
                    else        aD[gr * 4 + (lr - 4)] = v;
                }
            }
        }
    }
}

// ---------------- pull aggregation (unchanged — verified) ----------------

template <int MODE>
__global__ __launch_bounds__(128) void agg_kernel(const float* __restrict__ H,
                                                  const float* __restrict__ aS,
                                                  const float* __restrict__ aD,
                                                  const int* __restrict__ moff,
                                                  const int* __restrict__ mcsr,
                                                  const float* __restrict__ bias,
                                                  const int* __restrict__ list,
                                                  const int* __restrict__ inv,
                                                  const int* __restrict__ cntp,
                                                  float* __restrict__ out) {
    __shared__ int s_src[CAPDEG];
    __shared__ float s_as[CAPDEG * 4];
    __shared__ float s_w[4][CAPDEG];
    int t = threadIdx.x;
    int head = t >> 5;
    int jl = t & 31;
    int cnt = MODE ? 64 : *cntp;
    float bval = bias[t];
    for (int j = blockIdx.x; j < cnt; j += gridDim.x) {
        int n = list[j];
        int row = MODE ? inv[n] : j;
        int own = MODE ? row : n;
        int start = moff[row];
        int deg = moff[row + 1] - start;
        float ad_n = aD[own * HEADS + head];
        float as_self = aS[own * HEADS + head];
        float e_self = leaky(as_self + ad_n);
        float denom, acc;

        if (deg <= CAPDEG) {
            for (int i = t; i < deg; i += 128) {
                int s = mcsr[start + i];
                int si = MODE ? inv[s] : s;
                s_src[i] = si;
                ((float4*)s_as)[i] = ((const float4*)aS)[si];
            }
            __syncthreads();
            float lm = e_self;
            for (int i = jl; i < deg; i += 32)
                lm = fmaxf(lm, leaky(s_as[i * 4 + head] + ad_n));
#pragma unroll
            for (int msk = 16; msk > 0; msk >>= 1)
                lm = fmaxf(lm, __shfl_xor(lm, msk, 32));
            float lsum = 0.f;
            for (int i = jl; i < deg; i += 32) {
                float ww = __expf(leaky(s_as[i * 4 + head] + ad_n) - lm);
                s_w[head][i] = ww;
                lsum += ww;
            }
#pragma unroll
            for (int msk = 16; msk > 0; msk >>= 1)
                lsum += __shfl_xor(lsum, msk, 32);
            float w_self = __expf(e_self - lm);
            denom = lsum + w_self;
            __syncthreads();
            acc = w_self * H[(size_t)own * 128 + t];
            for (int i = 0; i < deg; ++i)
                acc += s_w[head][i] * H[(size_t)s_src[i] * 128 + t];
        } else {
            float m = e_self;
            for (int e = start; e < start + deg; ++e) {
                int s = mcsr[e];
                int si = MODE ? inv[s] : s;
                m = fmaxf(m, leaky(aS[si * HEADS + head] + ad_n));
            }
            float w_self = __expf(e_self - m);
            denom = w_self;
            acc = w_self * H[(size_t)own * 128 + t];
            for (int e = start; e < start + deg; ++e) {
                int s = mcsr[e];
                int si = MODE ? inv[s] : s;
                float ww = __expf(leaky(aS[si * HEADS + head] + ad_n) - m);
                denom += ww;
                acc += ww * H[(size_t)si * 128 + t];
            }
        }
        out[(size_t)j * 128 + t] = acc / denom + bval;
        __syncthreads();
    }
}

// ---------------- launch ----------------

extern "C" void kernel_launch(void* const* d_in, const int* in_sizes, int n_in,
                              void* d_out, int out_size, void* d_ws, size_t ws_size,
                              hipStream_t stream) {
    const float* x   = (const float*)d_in[0];
    const int*   ei  = (const int*)d_in[1];
    const int*   rts = (const int*)d_in[2];
    const float* W1  = (const float*)d_in[3];
    const float* a1s = (const float*)d_in[4];
    const float* a1d = (const float*)d_in[5];
    const float* b1  = (const float*)d_in[6];
    const float* W2  = (const float*)d_in[7];
    const float* a2s = (const float*)d_in[8];
    const float* a2d = (const float*)d_in[9];
    const float* b2  = (const float*)d_in[10];
    float* out = (float*)d_out;

    char* ws = (char*)d_ws;
    size_t o = 0;
    auto alloc = [&](size_t bytes) -> void* {
        void* p = ws + o;
        o += (bytes + 255) & ~(size_t)255;
        return p;
    };
    // zero region: rbits | flag1 | cnt | ecnt | mdeg
    unsigned long long* rbits = (unsigned long long*)alloc((size_t)NBW * 8);
    int* flag1 = (int*)alloc((size_t)N_NODES * 4);
    int* cnt   = (int*)alloc(4);
    int* ecnt  = (int*)alloc(4);
    int* mdeg  = (int*)alloc((size_t)CAP * 4);
    size_t zlen = o;
    unsigned long long* f1bits = (unsigned long long*)alloc((size_t)NBW * 8);
    int* list  = (int*)alloc((size_t)CAP * 4);
    int* inv   = (int*)alloc((size_t)N_NODES * 4);
    int* moff  = (int*)alloc((size_t)(CAP + 1) * 4);
    int* mcur  = (int*)alloc((size_t)CAP * 4);
    int* mcsr  = (int*)alloc((size_t)MCSR_CAP * 4);
    int* esrc  = (int*)alloc((size_t)MCSR_CAP * 4);
    int* erow  = (int*)alloc((size_t)MCSR_CAP * 4);
    unsigned short* wt_hi = (unsigned short*)alloc((size_t)2 * WT_L * 2);
    unsigned short* wt_lo = (unsigned short*)alloc((size_t)2 * WT_L * 2);
    float* h1  = (float*)alloc((size_t)N_NODES * 128 * 4);
    float* aS1 = (float*)alloc((size_t)N_NODES * HEADS * 4);
    float* aD1 = (float*)alloc((size_t)N_NODES * HEADS * 4);
    float* o1c = (float*)alloc((size_t)CAP * 128 * 4);
    float* h2c = (float*)alloc((size_t)CAP * 128 * 4);
    float* aS2 = (float*)alloc((size_t)CAP * HEADS * 4);
    float* aD2 = (float*)alloc((size_t)CAP * HEADS * 4);

    hipMemsetAsync(ws, 0, zlen, stream);

    const int EB = (N_EDGES / 4 + 255) / 256;   // 1563

    prep_kernel<<<144, 256, 0, stream>>>(W1, a1s, a1d, W2, a2s, a2d,
                                         wt_hi, wt_lo, rts, rbits, flag1);
    passA_kernel<<<EB, 256, 0, stream>>>(ei, rbits, flag1);
    compact_kernel<<<(N_NODES + 255) / 256, 256, 0, stream>>>(flag1, cnt, list, inv, f1bits);
    passE_kernel<<<EB, 256, 0, stream>>>(ei, f1bits, inv, ecnt, esrc, erow, mdeg);
    mini_scan_kernel<<<1, 1024, 0, stream>>>(mdeg, cnt, moff, mcur);
    scatter_mini_kernel<<<128, 256, 0, stream>>>(ecnt, esrc, erow, mcur, mcsr);

    // layer 1
    gemm_kernel<0, 0><<<(N_NODES + 127) / 128, 256, 0, stream>>>(
        x, wt_hi, wt_lo, h1, aS1, aD1, N_NODES, nullptr);
    agg_kernel<0><<<2048, 128, 0, stream>>>(h1, aS1, aD1, moff, mcsr, b1, list, inv, cnt, o1c);

    // layer 2
    gemm_kernel<1, 1><<<32, 256, 0, stream>>>(
        o1c, wt_hi + WT_L, wt_lo + WT_L, h2c, aS2, aD2, 0, cnt);
    agg_kernel<1><<<64, 128, 0, stream>>>(h2c, aS2, aD2, moff, mcsr, b2, rts, inv, cnt, out);
}

// Round 5
// 193.352 us; speedup vs baseline: 2.5913x; 1.2668x over previous
//
#include <hip/hip_runtime.h>
#include <hip/hip_bf16.h>

#define N_NODES 50000
#define N_EDGES 1600000
#define HEADS 4
#define NEG_SLOPE 0.2f
#define CAP 16384          // max |A1| (actual ~2100)
#define CAPDEG 512         // max staged in-degree in agg
#define MCSR_CAP (1 << 20) // mini edge-list capacity (actual ~69K)
#define NCOL 144           // 128 output cols + 16 alpha cols (8 used)
#define WT_L (NCOL * 128)  // per-layer wt elements
#define NBW 784            // u64 words for 50176-bit node mask
#define TSTRIDE 148        // padded f32 stride for epilogue transpose

typedef short short8 __attribute__((ext_vector_type(8)));
typedef float f32x4 __attribute__((ext_vector_type(4)));

__device__ __forceinline__ float leaky(float x) { return fmaxf(x, NEG_SLOPE * x); }

__device__ __forceinline__ unsigned short f2bf(float f) {
    unsigned int u = __builtin_bit_cast(unsigned int, f);
    u += 0x7fffu + ((u >> 16) & 1u);           // RNE to bf16
    return (unsigned short)(u >> 16);
}
__device__ __forceinline__ float bf2f(unsigned short s) {
    unsigned int u = ((unsigned int)s) << 16;
    return __builtin_bit_cast(float, u);
}

// ---------------- prep: W -> transposed bf16 hi/lo [layer][col][k], alpha cols fused;
// also marks roots (bitmask + int flags) ----------------

__global__ void prep_kernel(const float* __restrict__ W1, const float* __restrict__ a1s,
                            const float* __restrict__ a1d,
                            const float* __restrict__ W2, const float* __restrict__ a2s,
                            const float* __restrict__ a2d,
                            unsigned short* __restrict__ wt_hi, unsigned short* __restrict__ wt_lo,
                            const int* __restrict__ roots,
                            unsigned long long* __restrict__ rbits,
                            int* __restrict__ flag1) {
    int idx = blockIdx.x * 256 + threadIdx.x;       // 2*144*128 = 36864 total
    int layer = idx / WT_L;
    int rem = idx - layer * WT_L;
    int col = rem >> 7;
    int k = rem & 127;
    const float* W = layer ? W2 : W1;
    const float* as = layer ? a2s : a1s;
    const float* ad = layer ? a2d : a1d;
    float w = 0.f;
    if (col < 128) {
        w = W[k * 128 + col];
    } else if (col < 136) {
        int j = col - 128;
        int h = j & 3;
        const float* av = (j < 4) ? as : ad;
        float s = 0.f;
        for (int d = 0; d < 32; ++d) s += W[k * 128 + h * 32 + d] * av[h * 32 + d];
        w = s;
    }
    unsigned short hb = f2bf(w);
    wt_hi[idx] = hb;
    wt_lo[idx] = f2bf(w - bf2f(hb));
    if (blockIdx.x == 0 && threadIdx.x < 64) {
        int n = roots[threadIdx.x];
        atomicOr(&rbits[n >> 6], 1ull << (n & 63));
        flag1[n] = 1;
    }
}

// ---------------- pass A: flag1[src]=1 for edges whose dst is a root ----------------

__global__ __launch_bounds__(256) void passA_kernel(const int* __restrict__ ei,
                                                    const unsigned long long* __restrict__ rbits,
                                                    int* __restrict__ flag1) {
    __shared__ unsigned long long lmask[NBW];
    int t = threadIdx.x;
    for (int w = t; w < NBW; w += 256) lmask[w] = rbits[w];
    __syncthreads();
    int i = blockIdx.x * 256 + t;
    if (i * 4 >= N_EDGES) return;
    int4 s4 = ((const int4*)ei)[i];
    int4 d4 = ((const int4*)(ei + N_EDGES))[i];
    int ss[4] = {s4.x, s4.y, s4.z, s4.w};
    int dd[4] = {d4.x, d4.y, d4.z, d4.w};
#pragma unroll
    for (int j = 0; j < 4; ++j)
        if ((lmask[dd[j] >> 6] >> (dd[j] & 63)) & 1ull) flag1[ss[j]] = 1;
}

// ---------------- compact: wave-aggregated; also emits flag1 bitmask ----------------

__global__ __launch_bounds__(256) void compact_kernel(const int* __restrict__ flag1,
                                                      int* __restrict__ cnt,
                                                      int* __restrict__ list,
                                                      int* __restrict__ inv,
                                                      unsigned long long* __restrict__ f1bits) {
    int i = blockIdx.x * blockDim.x + threadIdx.x;
    int lane = threadIdx.x & 63;
    int f = (i < N_NODES) ? flag1[i] : 0;
    unsigned long long b = __ballot(f != 0);
    if (lane == 0) f1bits[i >> 6] = b;
    if (b) {
        int leader = (int)(__ffsll((long long)b) - 1);
        int base = 0;
        if (lane == leader) base = atomicAdd(cnt, __popcll(b));
        base = __shfl(base, leader, 64);
        if (f) {
            int p = base + __popcll(b & ((1ull << lane) - 1ull));
            if (p < CAP) { list[p] = i; inv[i] = p; }
        }
    }
}

// ---------------- pass E: append (src,row) for edges into A1; block-aggregated ----------------

__global__ __launch_bounds__(256) void passE_kernel(const int* __restrict__ ei,
                                                    const unsigned long long* __restrict__ f1bits,
                                                    const int* __restrict__ inv,
                                                    int* __restrict__ ecnt,
                                                    int* __restrict__ esrc, int* __restrict__ erow,
                                                    int* __restrict__ mdeg) {
    __shared__ unsigned long long lmask[NBW];
    __shared__ int bufS[1024], bufD[1024];
    __shared__ int lcnt, gbase;
    int t = threadIdx.x;
    for (int w = t; w < NBW; w += 256) lmask[w] = f1bits[w];
    if (t == 0) lcnt = 0;
    __syncthreads();
    int i = blockIdx.x * 256 + t;
    if (i * 4 < N_EDGES) {
        int4 s4 = ((const int4*)ei)[i];
        int4 d4 = ((const int4*)(ei + N_EDGES))[i];
        int ss[4] = {s4.x, s4.y, s4.z, s4.w};
        int dd[4] = {d4.x, d4.y, d4.z, d4.w};
#pragma unroll
        for (int j = 0; j < 4; ++j) {
            if ((lmask[dd[j] >> 6] >> (dd[j] & 63)) & 1ull) {
                int p = atomicAdd(&lcnt, 1);     // LDS atomic: cheap
                bufS[p] = ss[j]; bufD[p] = dd[j];
            }
        }
    }
    __syncthreads();
    if (t == 0) gbase = atomicAdd(ecnt, lcnt);   // ONE global atomic per block
    __syncthreads();
    int base = gbase, m = lcnt;
    for (int k = t; k < m; k += 256) {
        int p = base + k;
        if (p < MCSR_CAP) {
            int row = inv[bufD[k]];
            esrc[p] = bufS[k];
            erow[p] = row;
            atomicAdd(&mdeg[row], 1);            // distributed over ~2100 rows
        }
    }
}

__global__ __launch_bounds__(1024) void mini_scan_kernel(const int* __restrict__ mdeg,
                                                         const int* __restrict__ cntp,
                                                         int* __restrict__ moff,
                                                         int* __restrict__ mcur) {
    __shared__ int sums[1024];
    int cnt = *cntp;
    int chunk = (cnt + 1023) >> 10;
    int t = threadIdx.x;
    int begin = t * chunk;
    int endi = begin + chunk; if (endi > cnt) endi = cnt;
    int s = 0;
    for (int i = begin; i < endi; ++i) s += mdeg[i];
    sums[t] = s;
    __syncthreads();
    for (int o = 1; o < 1024; o <<= 1) {
        int x = (t >= o) ? sums[t - o] : 0;
        __syncthreads();
        sums[t] += x;
        __syncthreads();
    }
    int excl = sums[t] - s;
    for (int i = begin; i < endi; ++i) {
        int d = mdeg[i];
        moff[i] = excl; mcur[i] = excl;
        excl += d;
    }
    if (t == 1023) moff[cnt] = sums[1023];
}

__global__ void scatter_mini_kernel(const int* __restrict__ ecnt,
                                    const int* __restrict__ esrc, const int* __restrict__ erow,
                                    int* __restrict__ mcur, int* __restrict__ mcsr) {
    int total = *ecnt; if (total > MCSR_CAP) total = MCSR_CAP;
    int stride = gridDim.x * blockDim.x;
    for (int i = blockIdx.x * blockDim.x + threadIdx.x; i < total; i += stride) {
        int row = erow[i];
        int p = atomicAdd(&mcur[row], 1);
        mcsr[p] = esrc[i];
    }
}

// ---------------- MFMA GEMM (bf16x4 split) + fused alpha columns ----------------
// 512 threads = 8 waves; block tile 128 rows x 144 cols; wave w owns rows w*16..+15.
// ONE tile per block (grid == ntiles) so the W LDS region is dead after the K-loop
// and is reused as the epilogue transpose buffer (full-line coalesced H stores).

template <int RELU, int DYN>
__global__ __launch_bounds__(512, 1) void gemm_kernel(const float* __restrict__ A,
                                                      const unsigned short* __restrict__ wt_hi,
                                                      const unsigned short* __restrict__ wt_lo,
                                                      float* __restrict__ H,
                                                      float* __restrict__ aS,
                                                      float* __restrict__ aD,
                                                      int n_static, const int* __restrict__ cntp) {
    __shared__ float shf[128 * TSTRIDE];     // 75776 B; also holds W hi/lo as shorts
    short* shw = (short*)shf;
    int n = DYN ? *cntp : n_static;
    int ntiles = (n + 127) >> 7;
    int tile = blockIdx.x;
    if (tile >= ntiles) return;
    int t = threadIdx.x;
    // stage W hi/lo (16B granules, XOR-swizzled): 4608 granules / 512 threads = 9 iters
    for (int s = t; s < 2 * NCOL * 16; s += 512) {
        int half = s >= NCOL * 16;
        int rem = half ? s - NCOL * 16 : s;
        int col = rem >> 4;
        int kblk = rem & 15;
        const unsigned short* src = half ? wt_lo : wt_hi;
        short8 v = *(const short8*)(src + col * 128 + kblk * 8);
        int idx = ((col * 128 + kblk * 8) ^ ((col & 7) << 3)) + half * WT_L;
        *(short8*)(shw + idx) = v;
    }
    __syncthreads();
    int w = t >> 6;
    int l = t & 63;
    int lr = l & 15;
    int lq = l >> 4;
    int row0 = tile * 128;
    int wrow = row0 + w * 16;
    f32x4 acc[9];
#pragma unroll
    for (int ct = 0; ct < 9; ++ct) acc[ct] = (f32x4){0.f, 0.f, 0.f, 0.f};
#pragma unroll
    for (int kk = 0; kk < 4; ++kk) {
        int gr = wrow + lr;
        float4 p0 = make_float4(0.f, 0.f, 0.f, 0.f);
        float4 p1 = make_float4(0.f, 0.f, 0.f, 0.f);
        if (gr < n) {
            const float* p = A + (size_t)gr * 128 + kk * 32 + lq * 8;
            p0 = *(const float4*)p;
            p1 = *(const float4*)(p + 4);
        }
        short8 ah, al;
        float xv[8] = {p0.x, p0.y, p0.z, p0.w, p1.x, p1.y, p1.z, p1.w};
#pragma unroll
        for (int j = 0; j < 8; ++j) {
            float f = RELU ? fmaxf(xv[j], 0.f) : xv[j];
            unsigned short hb = f2bf(f);
            ah[j] = (short)hb;
            al[j] = (short)f2bf(f - bf2f(hb));
        }
#pragma unroll
        for (int ct = 0; ct < 9; ++ct) {
            int col = ct * 16 + lr;
            int base = (col * 128 + kk * 32 + lq * 8) ^ ((col & 7) << 3);
            short8 bh = *(const short8*)(shw + base);
            short8 bl = *(const short8*)(shw + base + WT_L);
            acc[ct] = __builtin_amdgcn_mfma_f32_16x16x32_bf16(ah, bh, acc[ct], 0, 0, 0);
            acc[ct] = __builtin_amdgcn_mfma_f32_16x16x32_bf16(ah, bl, acc[ct], 0, 0, 0);
            acc[ct] = __builtin_amdgcn_mfma_f32_16x16x32_bf16(al, bh, acc[ct], 0, 0, 0);
            acc[ct] = __builtin_amdgcn_mfma_f32_16x16x32_bf16(al, bl, acc[ct], 0, 0, 0);
        }
    }
    __syncthreads();   // all waves done reading W -> safe to reuse LDS
    // transpose: C frag layout col = lane&15, row = (lane>>4)*4 + reg [m89-verified]
    // LDS write: consecutive lr -> consecutive banks; row-groups offset 592B = 16 banks -> 2-way (free)
#pragma unroll
    for (int ct = 0; ct < 9; ++ct) {
#pragma unroll
        for (int r = 0; r < 4; ++r)
            shf[(w * 16 + lq * 4 + r) * TSTRIDE + ct * 16 + lr] = acc[ct][r];
    }
    __syncthreads();
    // H out: 2 rows x 512B contiguous per wave instruction (full 128B lines)
#pragma unroll
    for (int i = 0; i < 8; ++i) {
        int idx = t + i * 512;
        int row = idx >> 5;
        int c4 = idx & 31;
        int gr = row0 + row;
        if (gr < n)
            *(float4*)(H + (size_t)gr * 128 + c4 * 4) = *(const float4*)&shf[row * TSTRIDE + c4 * 4];
    }
    // alpha out (cols 128..135 of the transpose buffer)
#pragma unroll
    for (int i = 0; i < 2; ++i) {
        int idx = t + i * 512;
        int row = idx >> 3;
        int j = idx & 7;
        int gr = row0 + row;
        if (gr < n) {
            float v = shf[row * TSTRIDE + 128 + j];
            if (j < 4) aS[gr * 4 + j] = v;
            else       aD[gr * 4 + (j - 4)] = v;
        }
    }
}

// ---------------- pull aggregation (unchanged — verified) ----------------

template <int MODE>
__global__ __launch_bounds__(128) void agg_kernel(const float* __restrict__ H,
                                                  const float* __restrict__ aS,
                                                  const float* __restrict__ aD,
                                                  const int* __restrict__ moff,
                                                  const int* __restrict__ mcsr,
                                                  const float* __restrict__ bias,
                                                  const int* __restrict__ list,
                                                  const int* __restrict__ inv,
                                                  const int* __restrict__ cntp,
                                                  float* __restrict__ out) {
    __shared__ int s_src[CAPDEG];
    __shared__ float s_as[CAPDEG * 4];
    __shared__ float s_w[4][CAPDEG];
    int t = threadIdx.x;
    int head = t >> 5;
    int jl = t & 31;
    int cnt = MODE ? 64 : *cntp;
    float bval = bias[t];
    for (int j = blockIdx.x; j < cnt; j += gridDim.x) {
        int n = list[j];
        int row = MODE ? inv[n] : j;
        int own = MODE ? row : n;
        int start = moff[row];
        int deg = moff[row + 1] - start;
        float ad_n = aD[own * HEADS + head];
        float as_self = aS[own * HEADS + head];
        float e_self = leaky(as_self + ad_n);
        float denom, acc;

        if (deg <= CAPDEG) {
            for (int i = t; i < deg; i += 128) {
                int s = mcsr[start + i];
                int si = MODE ? inv[s] : s;
                s_src[i] = si;
                ((float4*)s_as)[i] = ((const float4*)aS)[si];
            }
            __syncthreads();
            float lm = e_self;
            for (int i = jl; i < deg; i += 32)
                lm = fmaxf(lm, leaky(s_as[i * 4 + head] + ad_n));
#pragma unroll
            for (int msk = 16; msk > 0; msk >>= 1)
                lm = fmaxf(lm, __shfl_xor(lm, msk, 32));
            float lsum = 0.f;
            for (int i = jl; i < deg; i += 32) {
                float ww = __expf(leaky(s_as[i * 4 + head] + ad_n) - lm);
                s_w[head][i] = ww;
                lsum += ww;
            }
#pragma unroll
            for (int msk = 16; msk > 0; msk >>= 1)
                lsum += __shfl_xor(lsum, msk, 32);
            float w_self = __expf(e_self - lm);
            denom = lsum + w_self;
            __syncthreads();
            acc = w_self * H[(size_t)own * 128 + t];
            for (int i = 0; i < deg; ++i)
                acc += s_w[head][i] * H[(size_t)s_src[i] * 128 + t];
        } else {
            float m = e_self;
            for (int e = start; e < start + deg; ++e) {
                int s = mcsr[e];
                int si = MODE ? inv[s] : s;
                m = fmaxf(m, leaky(aS[si * HEADS + head] + ad_n));
            }
            float w_self = __expf(e_self - m);
            denom = w_self;
            acc = w_self * H[(size_t)own * 128 + t];
            for (int e = start; e < start + deg; ++e) {
                int s = mcsr[e];
                int si = MODE ? inv[s] : s;
                float ww = __expf(leaky(aS[si * HEADS + head] + ad_n) - m);
                denom += ww;
                acc += ww * H[(size_t)si * 128 + t];
            }
        }
        out[(size_t)j * 128 + t] = acc / denom + bval;
        __syncthreads();
    }
}

// ---------------- launch ----------------

extern "C" void kernel_launch(void* const* d_in, const int* in_sizes, int n_in,
                              void* d_out, int out_size, void* d_ws, size_t ws_size,
                              hipStream_t stream) {
    const float* x   = (const float*)d_in[0];
    const int*   ei  = (const int*)d_in[1];
    const int*   rts = (const int*)d_in[2];
    const float* W1  = (const float*)d_in[3];
    const float* a1s = (const float*)d_in[4];
    const float* a1d = (const float*)d_in[5];
    const float* b1  = (const float*)d_in[6];
    const float* W2  = (const float*)d_in[7];
    const float* a2s = (const float*)d_in[8];
    const float* a2d = (const float*)d_in[9];
    const float* b2  = (const float*)d_in[10];
    float* out = (float*)d_out;

    char* ws = (char*)d_ws;
    size_t o = 0;
    auto alloc = [&](size_t bytes) -> void* {
        void* p = ws + o;
        o += (bytes + 255) & ~(size_t)255;
        return p;
    };
    // zero region: rbits | flag1 | cnt | ecnt | mdeg
    unsigned long long* rbits = (unsigned long long*)alloc((size_t)NBW * 8);
    int* flag1 = (int*)alloc((size_t)N_NODES * 4);
    int* cnt   = (int*)alloc(4);
    int* ecnt  = (int*)alloc(4);
    int* mdeg  = (int*)alloc((size_t)CAP * 4);
    size_t zlen = o;
    unsigned long long* f1bits = (unsigned long long*)alloc((size_t)NBW * 8);
    int* list  = (int*)alloc((size_t)CAP * 4);
    int* inv   = (int*)alloc((size_t)N_NODES * 4);
    int* moff  = (int*)alloc((size_t)(CAP + 1) * 4);
    int* mcur  = (int*)alloc((size_t)CAP * 4);
    int* mcsr  = (int*)alloc((size_t)MCSR_CAP * 4);
    int* esrc  = (int*)alloc((size_t)MCSR_CAP * 4);
    int* erow  = (int*)alloc((size_t)MCSR_CAP * 4);
    unsigned short* wt_hi = (unsigned short*)alloc((size_t)2 * WT_L * 2);
    unsigned short* wt_lo = (unsigned short*)alloc((size_t)2 * WT_L * 2);
    float* h1  = (float*)alloc((size_t)N_NODES * 128 * 4);
    float* aS1 = (float*)alloc((size_t)N_NODES * HEADS * 4);
    float* aD1 = (float*)alloc((size_t)N_NODES * HEADS * 4);
    float* o1c = (float*)alloc((size_t)CAP * 128 * 4);
    float* h2c = (float*)alloc((size_t)CAP * 128 * 4);
    float* aS2 = (float*)alloc((size_t)CAP * HEADS * 4);
    float* aD2 = (float*)alloc((size_t)CAP * HEADS * 4);

    hipMemsetAsync(ws, 0, zlen, stream);

    const int EB = (N_EDGES / 4 + 255) / 256;   // 1563

    prep_kernel<<<144, 256, 0, stream>>>(W1, a1s, a1d, W2, a2s, a2d,
                                         wt_hi, wt_lo, rts, rbits, flag1);
    passA_kernel<<<EB, 256, 0, stream>>>(ei, rbits, flag1);
    compact_kernel<<<(N_NODES + 255) / 256, 256, 0, stream>>>(flag1, cnt, list, inv, f1bits);
    passE_kernel<<<EB, 256, 0, stream>>>(ei, f1bits, inv, ecnt, esrc, erow, mdeg);
    mini_scan_kernel<<<1, 1024, 0, stream>>>(mdeg, cnt, moff, mcur);
    scatter_mini_kernel<<<128, 256, 0, stream>>>(ecnt, esrc, erow, mcur, mcsr);

    // layer 1: grid == ntiles (one tile per block; required for the LDS-reuse epilogue)
    gemm_kernel<0, 0><<<(N_NODES + 127) / 128, 512, 0, stream>>>(
        x, wt_hi, wt_lo, h1, aS1, aD1, N_NODES, nullptr);
    agg_kernel<0><<<2048, 128, 0, stream>>>(h1, aS1, aD1, moff, mcsr, b1, list, inv, cnt, o1c);

    // layer 2: grid covers CAP rows; blocks beyond ntiles exit immediately
    gemm_kernel<1, 1><<<CAP / 128, 512, 0, stream>>>(
        o1c, wt_hi + WT_L, wt_lo + WT_L, h2c, aS2, aD2, 0, cnt);
    agg_kernel<1><<<64, 128, 0, stream>>>(h2c, aS2, aD2, moff, mcsr, b2, rts, inv, cnt, out);
}

// Round 6
// 162.366 us; speedup vs baseline: 3.0859x; 1.1908x over previous
//
#include <hip/hip_runtime.h>
#include <hip/hip_bf16.h>

#define N_NODES 50000
#define N_EDGES 1600000
#define HEADS 4
#define NEG_SLOPE 0.2f
#define CAP 16384          // max |A1| (actual ~2100)
#define CAPDEG 256         // bucket stride == max in-degree staged (actual max ~70)
#define NCOL 144           // 128 output cols + 16 alpha cols (8 used)
#define WT_L (NCOL * 128)  // per-layer wt elements
#define NBW 784            // u64 words for 50176-bit node mask
#define TSTRIDE 148        // padded f32 stride for epilogue transpose

typedef short short8 __attribute__((ext_vector_type(8)));
typedef float f32x4 __attribute__((ext_vector_type(4)));

__device__ __forceinline__ float leaky(float x) { return fmaxf(x, NEG_SLOPE * x); }

__device__ __forceinline__ unsigned short f2bf(float f) {
    unsigned int u = __builtin_bit_cast(unsigned int, f);
    u += 0x7fffu + ((u >> 16) & 1u);           // RNE to bf16
    return (unsigned short)(u >> 16);
}
__device__ __forceinline__ float bf2f(unsigned short s) {
    unsigned int u = ((unsigned int)s) << 16;
    return __builtin_bit_cast(float, u);
}

// ---------------- prep: W -> transposed bf16 hi/lo [layer][col][k], alpha cols fused;
// also zeroes flag1 / mdeg / cnt (replaces the memset dispatch) ----------------

__global__ __launch_bounds__(256) void prep_kernel(const float* __restrict__ W1,
                            const float* __restrict__ a1s, const float* __restrict__ a1d,
                            const float* __restrict__ W2,
                            const float* __restrict__ a2s, const float* __restrict__ a2d,
                            unsigned short* __restrict__ wt_hi, unsigned short* __restrict__ wt_lo,
                            int* __restrict__ flag1, int* __restrict__ mdeg,
                            int* __restrict__ cnt) {
    int idx = blockIdx.x * 256 + threadIdx.x;       // 2*144*128 = 36864 total
    // zero region (no dependency hazard: consumers are later kernels)
    for (int z = idx; z < N_NODES; z += 36864) flag1[z] = 0;
    for (int z = idx; z < CAP; z += 36864) mdeg[z] = 0;
    if (idx == 0) *cnt = 0;

    int layer = idx / WT_L;
    int rem = idx - layer * WT_L;
    int col = rem >> 7;
    int k = rem & 127;
    const float* W = layer ? W2 : W1;
    const float* as = layer ? a2s : a1s;
    const float* ad = layer ? a2d : a1d;
    float w = 0.f;
    if (col < 128) {
        w = W[k * 128 + col];
    } else if (col < 136) {
        int j = col - 128;
        int h = j & 3;
        const float* av = (j < 4) ? as : ad;
        float s = 0.f;
        for (int d = 0; d < 32; ++d) s += W[k * 128 + h * 32 + d] * av[h * 32 + d];
        w = s;
    }
    unsigned short hb = f2bf(w);
    wt_hi[idx] = hb;
    wt_lo[idx] = f2bf(w - bf2f(hb));
}

// ---------------- pass A: flag1[src]=1 for edges whose dst is a root ----------------
// root bitmask built in LDS from the 64 root ids directly (no global mask buffer).

__global__ __launch_bounds__(256) void passA_kernel(const int* __restrict__ ei,
                                                    const int* __restrict__ rts,
                                                    int* __restrict__ flag1) {
    __shared__ unsigned long long lmask[NBW];
    int t = threadIdx.x;
    for (int w = t; w < NBW; w += 256) lmask[w] = 0ull;
    __syncthreads();
    if (t < 64) {
        int n = rts[t];
        atomicOr(&lmask[n >> 6], 1ull << (n & 63));
        if (blockIdx.x == 0) flag1[n] = 1;   // roots are always in A1
    }
    __syncthreads();
    int i = blockIdx.x * 256 + t;
    if (i * 4 >= N_EDGES) return;
    int4 s4 = ((const int4*)ei)[i];
    int4 d4 = ((const int4*)(ei + N_EDGES))[i];
    int ss[4] = {s4.x, s4.y, s4.z, s4.w};
    int dd[4] = {d4.x, d4.y, d4.z, d4.w};
#pragma unroll
    for (int j = 0; j < 4; ++j)
        if ((lmask[dd[j] >> 6] >> (dd[j] & 63)) & 1ull) flag1[ss[j]] = 1;
}

// ---------------- compact: wave-aggregated; also emits flag1 bitmask ----------------

__global__ __launch_bounds__(256) void compact_kernel(const int* __restrict__ flag1,
                                                      int* __restrict__ cnt,
                                                      int* __restrict__ list,
                                                      int* __restrict__ inv,
                                                      unsigned long long* __restrict__ f1bits) {
    int i = blockIdx.x * blockDim.x + threadIdx.x;
    int lane = threadIdx.x & 63;
    int f = (i < N_NODES) ? flag1[i] : 0;
    unsigned long long b = __ballot(f != 0);
    if (lane == 0) f1bits[i >> 6] = b;
    if (b) {
        int leader = (int)(__ffsll((long long)b) - 1);
        int base = 0;
        if (lane == leader) base = atomicAdd(cnt, __popcll(b));
        base = __shfl(base, leader, 64);
        if (f) {
            int p = base + __popcll(b & ((1ull << lane) - 1ull));
            if (p < CAP) { list[p] = i; inv[i] = p; }
        }
    }
}

// ---------------- pass E: direct-bucket edges whose dst is in A1 ----------------
// slot = atomicAdd(mdeg[row]) distributed over ~2100 rows; no CSR scan/scatter needed.

__global__ __launch_bounds__(256) void passE_kernel(const int* __restrict__ ei,
                                                    const unsigned long long* __restrict__ f1bits,
                                                    const int* __restrict__ inv,
                                                    int* __restrict__ mdeg,
                                                    int* __restrict__ bucket) {
    __shared__ unsigned long long lmask[NBW];
    int t = threadIdx.x;
    for (int w = t; w < NBW; w += 256) lmask[w] = f1bits[w];
    __syncthreads();
    int i = blockIdx.x * 256 + t;
    if (i * 4 >= N_EDGES) return;
    int4 s4 = ((const int4*)ei)[i];
    int4 d4 = ((const int4*)(ei + N_EDGES))[i];
    int ss[4] = {s4.x, s4.y, s4.z, s4.w};
    int dd[4] = {d4.x, d4.y, d4.z, d4.w};
#pragma unroll
    for (int j = 0; j < 4; ++j) {
        if ((lmask[dd[j] >> 6] >> (dd[j] & 63)) & 1ull) {
            int row = inv[dd[j]];
            int sl = atomicAdd(&mdeg[row], 1);
            if (sl < CAPDEG) bucket[row * CAPDEG + sl] = ss[j];
        }
    }
}

// ---------------- MFMA GEMM (bf16x4 split) + fused alpha columns ----------------
// 512 threads = 8 waves; block tile 128 rows x 144 cols; wave w owns rows w*16..+15.
// ONE tile per block; the W LDS region is reused as the epilogue transpose buffer.

template <int RELU, int DYN>
__global__ __launch_bounds__(512, 1) void gemm_kernel(const float* __restrict__ A,
                                                      const unsigned short* __restrict__ wt_hi,
                                                      const unsigned short* __restrict__ wt_lo,
                                                      float* __restrict__ H,
                                                      float* __restrict__ aS,
                                                      float* __restrict__ aD,
                                                      int n_static, const int* __restrict__ cntp) {
    __shared__ float shf[128 * TSTRIDE];     // 75776 B; also holds W hi/lo as shorts
    short* shw = (short*)shf;
    int n = DYN ? *cntp : n_static;
    int ntiles = (n + 127) >> 7;
    int tile = blockIdx.x;
    if (tile >= ntiles) return;
    int t = threadIdx.x;
    for (int s = t; s < 2 * NCOL * 16; s += 512) {
        int half = s >= NCOL * 16;
        int rem = half ? s - NCOL * 16 : s;
        int col = rem >> 4;
        int kblk = rem & 15;
        const unsigned short* src = half ? wt_lo : wt_hi;
        short8 v = *(const short8*)(src + col * 128 + kblk * 8);
        int idx = ((col * 128 + kblk * 8) ^ ((col & 7) << 3)) + half * WT_L;
        *(short8*)(shw + idx) = v;
    }
    __syncthreads();
    int w = t >> 6;
    int l = t & 63;
    int lr = l & 15;
    int lq = l >> 4;
    int row0 = tile * 128;
    int wrow = row0 + w * 16;
    f32x4 acc[9];
#pragma unroll
    for (int ct = 0; ct < 9; ++ct) acc[ct] = (f32x4){0.f, 0.f, 0.f, 0.f};
#pragma unroll
    for (int kk = 0; kk < 4; ++kk) {
        int gr = wrow + lr;
        float4 p0 = make_float4(0.f, 0.f, 0.f, 0.f);
        float4 p1 = make_float4(0.f, 0.f, 0.f, 0.f);
        if (gr < n) {
            const float* p = A + (size_t)gr * 128 + kk * 32 + lq * 8;
            p0 = *(const float4*)p;
            p1 = *(const float4*)(p + 4);
        }
        short8 ah, al;
        float xv[8] = {p0.x, p0.y, p0.z, p0.w, p1.x, p1.y, p1.z, p1.w};
#pragma unroll
        for (int j = 0; j < 8; ++j) {
            float f = RELU ? fmaxf(xv[j], 0.f) : xv[j];
            unsigned short hb = f2bf(f);
            ah[j] = (short)hb;
            al[j] = (short)f2bf(f - bf2f(hb));
        }
#pragma unroll
        for (int ct = 0; ct < 9; ++ct) {
            int col = ct * 16 + lr;
            int base = (col * 128 + kk * 32 + lq * 8) ^ ((col & 7) << 3);
            short8 bh = *(const short8*)(shw + base);
            short8 bl = *(const short8*)(shw + base + WT_L);
            acc[ct] = __builtin_amdgcn_mfma_f32_16x16x32_bf16(ah, bh, acc[ct], 0, 0, 0);
            acc[ct] = __builtin_amdgcn_mfma_f32_16x16x32_bf16(ah, bl, acc[ct], 0, 0, 0);
            acc[ct] = __builtin_amdgcn_mfma_f32_16x16x32_bf16(al, bh, acc[ct], 0, 0, 0);
            acc[ct] = __builtin_amdgcn_mfma_f32_16x16x32_bf16(al, bl, acc[ct], 0, 0, 0);
        }
    }
    __syncthreads();   // all waves done reading W -> safe to reuse LDS
    // transpose: C frag layout col = lane&15, row = (lane>>4)*4 + reg [m89-verified]
#pragma unroll
    for (int ct = 0; ct < 9; ++ct) {
#pragma unroll
        for (int r = 0; r < 4; ++r)
            shf[(w * 16 + lq * 4 + r) * TSTRIDE + ct * 16 + lr] = acc[ct][r];
    }
    __syncthreads();
    // H out: full 128B-line coalesced stores
#pragma unroll
    for (int i = 0; i < 8; ++i) {
        int idx = t + i * 512;
        int row = idx >> 5;
        int c4 = idx & 31;
        int gr = row0 + row;
        if (gr < n)
            *(float4*)(H + (size_t)gr * 128 + c4 * 4) = *(const float4*)&shf[row * TSTRIDE + c4 * 4];
    }
    // alpha out as float4 per row
    if (t < 256) {
        int row = t >> 1, q = t & 1;
        int gr = row0 + row;
        if (gr < n) {
            float4 v = *(const float4*)&shf[row * TSTRIDE + 128 + q * 4];
            if (q == 0) *(float4*)(aS + (size_t)gr * 4) = v;
            else        *(float4*)(aD + (size_t)gr * 4) = v;
        }
    }
}

// ---------------- pull aggregation: max-free softmax, 2 phases, 1 barrier ----------------
// Logits are bounded (|e| < ~6 << 88): exp(e)/sum(exp(e)) == exp(e-max)/sum(exp(e-max)).

template <int MODE>
__global__ __launch_bounds__(128) void agg_kernel(const float* __restrict__ H,
                                                  const float* __restrict__ aS,
                                                  const float* __restrict__ aD,
                                                  const int* __restrict__ mdeg,
                                                  const int* __restrict__ bucket,
                                                  const float* __restrict__ bias,
                                                  const int* __restrict__ list,
                                                  const int* __restrict__ inv,
                                                  const int* __restrict__ cntp,
                                                  float* __restrict__ out) {
    __shared__ int s_src[CAPDEG];
    __shared__ float s_w[4][CAPDEG + 1];   // +1 pad: the 4 heads' reads land on distinct banks
    int t = threadIdx.x;
    int head = t >> 5;
    int cnt = MODE ? 64 : *cntp;
    float bval = bias[t];
    for (int j = blockIdx.x; j < cnt; j += gridDim.x) {
        int n = list[j];
        int row = MODE ? inv[n] : j;     // bucket row
        int own = MODE ? row : n;        // row index into H/aS/aD
        int deg = mdeg[row]; if (deg > CAPDEG) deg = CAPDEG;
        float4 adv = ((const float4*)aD)[own];
        for (int i = t; i < deg; i += 128) {
            int s = bucket[row * CAPDEG + i];
            int si = MODE ? inv[s] : s;
            s_src[i] = si;
            float4 a4 = ((const float4*)aS)[si];
            s_w[0][i] = __expf(leaky(a4.x + adv.x));
            s_w[1][i] = __expf(leaky(a4.y + adv.y));
            s_w[2][i] = __expf(leaky(a4.z + adv.z));
            s_w[3][i] = __expf(leaky(a4.w + adv.w));
        }
        float w_self = __expf(leaky(aS[own * 4 + head] + aD[own * 4 + head]));
        __syncthreads();
        float denom = w_self;
        float acc = w_self * H[(size_t)own * 128 + t];
        for (int i = 0; i < deg; ++i) {
            float wv = s_w[head][i];
            denom += wv;
            acc += wv * H[(size_t)s_src[i] * 128 + t];
        }
        out[(size_t)j * 128 + t] = acc / denom + bval;
        __syncthreads();   // protect LDS before next grid-stride iteration
    }
}

// ---------------- launch ----------------

extern "C" void kernel_launch(void* const* d_in, const int* in_sizes, int n_in,
                              void* d_out, int out_size, void* d_ws, size_t ws_size,
                              hipStream_t stream) {
    const float* x   = (const float*)d_in[0];
    const int*   ei  = (const int*)d_in[1];
    const int*   rts = (const int*)d_in[2];
    const float* W1  = (const float*)d_in[3];
    const float* a1s = (const float*)d_in[4];
    const float* a1d = (const float*)d_in[5];
    const float* b1  = (const float*)d_in[6];
    const float* W2  = (const float*)d_in[7];
    const float* a2s = (const float*)d_in[8];
    const float* a2d = (const float*)d_in[9];
    const float* b2  = (const float*)d_in[10];
    float* out = (float*)d_out;

    char* ws = (char*)d_ws;
    size_t o = 0;
    auto alloc = [&](size_t bytes) -> void* {
        void* p = ws + o;
        o += (bytes + 255) & ~(size_t)255;
        return p;
    };
    int* flag1 = (int*)alloc((size_t)N_NODES * 4);          // zeroed by prep
    int* cnt   = (int*)alloc(4);                            // zeroed by prep
    int* mdeg  = (int*)alloc((size_t)CAP * 4);              // zeroed by prep
    unsigned long long* f1bits = (unsigned long long*)alloc((size_t)NBW * 8); // fully written by compact
    int* list  = (int*)alloc((size_t)CAP * 4);
    int* inv   = (int*)alloc((size_t)N_NODES * 4);
    int* bucket = (int*)alloc((size_t)CAP * CAPDEG * 4);    // 16.8 MB
    unsigned short* wt_hi = (unsigned short*)alloc((size_t)2 * WT_L * 2);
    unsigned short* wt_lo = (unsigned short*)alloc((size_t)2 * WT_L * 2);
    float* h1  = (float*)alloc((size_t)N_NODES * 128 * 4);
    float* aS1 = (float*)alloc((size_t)N_NODES * HEADS * 4);
    float* aD1 = (float*)alloc((size_t)N_NODES * HEADS * 4);
    float* o1c = (float*)alloc((size_t)CAP * 128 * 4);
    float* h2c = (float*)alloc((size_t)CAP * 128 * 4);
    float* aS2 = (float*)alloc((size_t)CAP * HEADS * 4);
    float* aD2 = (float*)alloc((size_t)CAP * HEADS * 4);

    const int EB = (N_EDGES / 4 + 255) / 256;   // 1563

    prep_kernel<<<144, 256, 0, stream>>>(W1, a1s, a1d, W2, a2s, a2d,
                                         wt_hi, wt_lo, flag1, mdeg, cnt);
    passA_kernel<<<EB, 256, 0, stream>>>(ei, rts, flag1);
    compact_kernel<<<(N_NODES + 255) / 256, 256, 0, stream>>>(flag1, cnt, list, inv, f1bits);
    passE_kernel<<<EB, 256, 0, stream>>>(ei, f1bits, inv, mdeg, bucket);

    // layer 1
    gemm_kernel<0, 0><<<(N_NODES + 127) / 128, 512, 0, stream>>>(
        x, wt_hi, wt_lo, h1, aS1, aD1, N_NODES, nullptr);
    agg_kernel<0><<<2048, 128, 0, stream>>>(h1, aS1, aD1, mdeg, bucket, b1, list, inv, cnt, o1c);

    // layer 2
    gemm_kernel<1, 1><<<CAP / 128, 512, 0, stream>>>(
        o1c, wt_hi + WT_L, wt_lo + WT_L, h2c, aS2, aD2, 0, cnt);
    agg_kernel<1><<<64, 128, 0, stream>>>(h2c, aS2, aD2, mdeg, bucket, b2, rts, inv, cnt, out);
}